// Round 2
// baseline (165.624 us; speedup 1.0000x reference)
//
#include <hip/hip_runtime.h>

typedef unsigned short u16;
typedef __attribute__((ext_vector_type(4))) float f32x4;
typedef __attribute__((ext_vector_type(8))) short s16x8;

static constexpr int N_ = 4096;
static constexpr int D_ = 1024;

__device__ __forceinline__ u16 f2bf(float f) {
  unsigned u = __float_as_uint(f);
  u += 0x7FFFu + ((u >> 16) & 1u);   // RNE
  return (u16)(u >> 16);
}

__device__ __forceinline__ f32x4 zero4() {
  f32x4 z; z[0] = 0.f; z[1] = 0.f; z[2] = 0.f; z[3] = 0.f; return z;
}

// ---------------- K0: WpB bf16 conversion + M = Pow @ Wsum (bf16) ----------------
// blocks 0..15: WpB; blocks 16..143: (b,tile) -> M rows
__global__ __launch_bounds__(256) void k_prep(
    const float* __restrict__ Wpm, const float* __restrict__ piw,
    const float* __restrict__ pw, u16* __restrict__ WpB,
    u16* __restrict__ MB) {
  int bid = blockIdx.x, tid = threadIdx.x;
  if (bid < 16) {
    size_t i0 = (size_t)bid * 4096;
    for (int idx = tid; idx < 4096; idx += 256)
      WpB[i0 + idx] = f2bf(piw[i0 + idx]);
    return;
  }
  __shared__ float Ws[64][65];
  int idx2 = bid - 16;
  int b = idx2 >> 4, t = idx2 & 15;
  // Wsum_b into LDS
  for (int idx = tid; idx < 4096; idx += 256) {
    float s = 0.f;
#pragma unroll
    for (int k = 0; k < 8; ++k)
      s += Wpm[((size_t)(b * 8 + k)) * 4096 + idx];
    Ws[idx >> 6][idx & 63] = s;
  }
  __syncthreads();
  // M[d][p] = sum_q Pow[d][q] * Wsum[q][p], rows d in [t*64, t*64+64)
  u16* mb = MB + ((size_t)b << 16);
  for (int oidx = tid; oidx < 4096; oidx += 256) {
    int r = oidx >> 6, c = oidx & 63;
    int drow = t * 64 + r;
    const float* prow = pw + (size_t)drow * 64;
    float acc = 0.f;
#pragma unroll 8
    for (int q = 0; q < 64; ++q) acc += prow[q] * Ws[q][c];
    mb[(size_t)drow * 64 + c] = f2bf(acc);
  }
}

// ---------------- K1: fused read/commit main pass ----------------
// grid = 8 batches * 64 row-tiles, 512 threads (8 waves), 64 rows/block.
// wave w: wm = w&3 selects 16-row tile, wk = w>>2 selects K-half / N-half.
__global__ __launch_bounds__(512, 4) void k_main(
    const float* __restrict__ H, const float* __restrict__ Sur,
    const float* __restrict__ pib, const float* __restrict__ pob,
    const float* __restrict__ sscale_p, const float* __restrict__ sbias_p,
    const u16* __restrict__ WpB, const u16* __restrict__ MB,
    float* __restrict__ Gacc, float* __restrict__ out) {
  __shared__ float preF[64][68];  // wk=1 partial pre (f32)
  __shared__ u16 preRP[64][72];   // pre (with bias), bf16
  __shared__ u16 wRP[64][72];     // sqrt(s)*pre, bf16
  __shared__ float sqs[64];

  const int tid = threadIdx.x;
  const int lane = tid & 63;
  const int w = tid >> 6;
  const int wm = w & 3;
  const int wk = w >> 2;
  const int llo = lane & 15;
  const int lhi = lane >> 4;
  const int b = blockIdx.x >> 6;
  const int row0 = (blockIdx.x & 63) * 64;

  // ---- surprise row norms -> sqrt(sigmoid(scale*mag+bias)), 8 rows/wave ----
  {
    int r = w * 8 + (lane >> 3);
    const float* p = Sur + ((size_t)b * N_ + row0 + r) * D_ + (lane & 7) * 4;
    float a0 = 0.f, a1 = 0.f;
#pragma unroll 8
    for (int j = 0; j < 32; j += 2) {
      float4 v = *(const float4*)(p + j * 32);
      float4 v2 = *(const float4*)(p + j * 32 + 32);
      a0 += v.x * v.x + v.y * v.y + v.z * v.z + v.w * v.w;
      a1 += v2.x * v2.x + v2.y * v2.y + v2.z * v2.z + v2.w * v2.w;
    }
    float a = a0 + a1;
    a += __shfl_xor(a, 1, 64);
    a += __shfl_xor(a, 2, 64);
    a += __shfl_xor(a, 4, 64);
    if ((lane & 7) == 0) {
      float mag = sqrtf(a);
      float s = 1.f / (1.f + __expf(-(sscale_p[0] * mag + sbias_p[0])));
      sqs[r] = sqrtf(s);
    }
  }

  // ---- phase A: pre = H @ Wp^T, K split across wk (512 each) ----
  f32x4 accA[4];
#pragma unroll
  for (int t = 0; t < 4; ++t) accA[t] = zero4();
  {
    const float* hrow =
        H + ((size_t)b * N_ + row0 + wm * 16 + llo) * D_ + wk * 512 + lhi * 8;
    const u16* wp0 = WpB + (size_t)llo * 1024 + wk * 512 + lhi * 8;
#pragma unroll 2
    for (int k0 = 0; k0 < 512; k0 += 32) {
      float4 a0 = *(const float4*)(hrow + k0);
      float4 a1 = *(const float4*)(hrow + k0 + 4);
      s16x8 af;
      af[0] = (short)f2bf(a0.x); af[1] = (short)f2bf(a0.y);
      af[2] = (short)f2bf(a0.z); af[3] = (short)f2bf(a0.w);
      af[4] = (short)f2bf(a1.x); af[5] = (short)f2bf(a1.y);
      af[6] = (short)f2bf(a1.z); af[7] = (short)f2bf(a1.w);
#pragma unroll
      for (int t = 0; t < 4; ++t) {
        s16x8 bf = *(const s16x8*)(wp0 + (size_t)t * 16 * 1024 + k0);
        accA[t] = __builtin_amdgcn_mfma_f32_16x16x32_bf16(af, bf, accA[t], 0, 0, 0);
      }
    }
  }
  if (wk == 1) {
#pragma unroll
    for (int t = 0; t < 4; ++t)
#pragma unroll
      for (int r = 0; r < 4; ++r)
        preF[wm * 16 + lhi * 4 + r][t * 16 + llo] = accA[t][r];
  }
  __syncthreads();
  if (wk == 0) {
#pragma unroll
    for (int t = 0; t < 4; ++t) {
      float bias = pib[t * 16 + llo];
#pragma unroll
      for (int r = 0; r < 4; ++r) {
        int row = wm * 16 + lhi * 4 + r;
        float v = accA[t][r] + preF[row][t * 16 + llo] + bias;
        preRP[row][t * 16 + llo] = f2bf(v);
        wRP[row][t * 16 + llo] = f2bf(v * sqs[row]);
      }
    }
  }
  __syncthreads();

  // ---- phase G: G += weighted^T @ weighted, rows split across wk ----
  {
    f32x4 accG[4];
#pragma unroll
    for (int t = 0; t < 4; ++t) accG[t] = zero4();
    int kbase = wk * 32;
    s16x8 ag;
#pragma unroll
    for (int j = 0; j < 8; ++j)
      ag[j] = (short)wRP[kbase + lhi * 8 + j][wm * 16 + llo];
#pragma unroll
    for (int t = 0; t < 4; ++t) {
      s16x8 bg;
#pragma unroll
      for (int j = 0; j < 8; ++j)
        bg[j] = (short)wRP[kbase + lhi * 8 + j][t * 16 + llo];
      accG[t] = __builtin_amdgcn_mfma_f32_16x16x32_bf16(ag, bg, accG[t], 0, 0, 0);
    }
    float* gb = Gacc + (size_t)b * 4096;
#pragma unroll
    for (int t = 0; t < 4; ++t)
#pragma unroll
      for (int r = 0; r < 4; ++r)
        atomicAdd(gb + (wm * 16 + lhi * 4 + r) * 64 + t * 16 + llo, accG[t][r]);
  }

  // ---- phase D: pm_read = pre @ M^T + bias, N-cols split across wk ----
  {
    s16x8 ad0 = *(const s16x8*)&preRP[wm * 16 + llo][lhi * 8];
    s16x8 ad1 = *(const s16x8*)&preRP[wm * 16 + llo][32 + lhi * 8];
    const u16* mb = MB + ((size_t)b << 16);
    float* orow = out + ((size_t)b * N_ + row0 + wm * 16) * D_;
    int nend = wk * 512 + 512;
    for (int n0 = wk * 512; n0 < nend; n0 += 16) {
      s16x8 b0 = *(const s16x8*)(mb + (size_t)(n0 + llo) * 64 + lhi * 8);
      s16x8 b1 = *(const s16x8*)(mb + (size_t)(n0 + llo) * 64 + 32 + lhi * 8);
      f32x4 acc = zero4();
      acc = __builtin_amdgcn_mfma_f32_16x16x32_bf16(ad0, b0, acc, 0, 0, 0);
      acc = __builtin_amdgcn_mfma_f32_16x16x32_bf16(ad1, b1, acc, 0, 0, 0);
      float bias = pob[n0 + llo];
#pragma unroll
      for (int r = 0; r < 4; ++r)
        orow[(size_t)(lhi * 4 + r) * D_ + n0 + llo] = acc[r] + bias;
    }
  }
}

// ---------------- K2: W_new = W_pm @ (decay*I + beta*G/N), frob clip ----------------
__global__ __launch_bounds__(256) void k_wnew(
    const float* __restrict__ Wpm, const float* __restrict__ Gacc,
    const float* __restrict__ rbeta, const float* __restrict__ rdecay,
    float* __restrict__ outW) {
  __shared__ float Wk[64][66];
  __shared__ float Gl[64][66];
  __shared__ float red[4];
  int bk = blockIdx.x;
  int b = bk >> 3, k = bk & 7;
  int tid = threadIdx.x;
  const float* wsrc = Wpm + (size_t)bk * 4096;
  const float* gsrc = Gacc + (size_t)b * 4096;
  for (int idx = tid; idx < 4096; idx += 256) {
    Wk[idx >> 6][idx & 63] = wsrc[idx];
    Gl[idx >> 6][idx & 63] = gsrc[idx];
  }
  __syncthreads();
  float beta = log1pf(__expf(rbeta[k]));
  float decay = 1.f / (1.f + __expf(-rdecay[k]));
  float bn = beta * (1.f / 4096.f);
  int q = tid & 63;
  int rbase = tid >> 6;
  float vals[16];
  float ss = 0.f;
#pragma unroll
  for (int i = 0; i < 16; ++i) {
    int row = i * 4 + rbase;
    float acc = 0.f;
#pragma unroll 8
    for (int j = 0; j < 64; ++j) acc += Wk[row][j] * Gl[j][q];
    float v = decay * Wk[row][q] + bn * acc;
    vals[i] = v;
    ss += v * v;
  }
#pragma unroll
  for (int m = 1; m < 64; m <<= 1) ss += __shfl_xor(ss, m, 64);
  if ((tid & 63) == 0) red[tid >> 6] = ss;
  __syncthreads();
  float frob = sqrtf(red[0] + red[1] + red[2] + red[3]);
  float scale = fminf(16.f / fmaxf(frob, 1e-8f), 1.f);
  float* dst = outW + (size_t)bk * 4096;
#pragma unroll
  for (int i = 0; i < 16; ++i) dst[i * 256 + tid] = vals[i] * scale;
}

extern "C" void kernel_launch(void* const* d_in, const int* in_sizes, int n_in,
                              void* d_out, int out_size, void* d_ws, size_t ws_size,
                              hipStream_t stream) {
  const float* H      = (const float*)d_in[0];
  const float* Sur    = (const float*)d_in[1];
  const float* Wpm    = (const float*)d_in[2];
  const float* piw    = (const float*)d_in[3];
  const float* pib    = (const float*)d_in[4];
  const float* pw     = (const float*)d_in[5];
  const float* pob    = (const float*)d_in[6];
  const float* rbeta  = (const float*)d_in[7];
  const float* rdecay = (const float*)d_in[8];
  const float* sscale = (const float*)d_in[9];
  const float* sbias  = (const float*)d_in[10];
  float* out = (float*)d_out;

  char* ws = (char*)d_ws;
  float* Gacc = (float*)(ws);                 // [8][64][64] f32   = 131072 B
  u16* WpB    = (u16*)(ws + 131072);          // [64][1024] bf16   = 131072 B
  u16* MB     = (u16*)(ws + 262144);          // [8][1024][64] bf16 = 1 MB

  hipMemsetAsync(Gacc, 0, 131072, stream);
  k_prep<<<144, 256, 0, stream>>>(Wpm, piw, pw, WpB, MB);
  k_main<<<512, 512, 0, stream>>>(H, Sur, pib, pob, sscale, sbias,
                                  WpB, MB, Gacc, out);
  k_wnew<<<64, 256, 0, stream>>>(Wpm, Gacc, rbeta, rdecay,
                                 out + (size_t)8 * 4096 * 1024);
}